// Round 11
// baseline (215.449 us; speedup 1.0000x reference)
//
#include <hip/hip_runtime.h>
#include <cmath>

#define BB 4
#define CC 128
#define HH 64
#define WW 64
#define SP 4096   // H*W
#define NG 32     // groups
#define TT 64     // attention uv-tile width
#define NS 2      // attention uv split factor
#define PSZ ((size_t)BB * SP * CC)   // partial tensor elements

typedef __bf16 bf16x8 __attribute__((ext_vector_type(8)));
typedef __bf16 bf16x4 __attribute__((ext_vector_type(4)));
typedef float  f32x4  __attribute__((ext_vector_type(4)));

__device__ __forceinline__ float silu_f(float v) {
    return v / (1.f + __expf(-v));
}

__device__ __forceinline__ float fast_exp2(float x) {
    return exp2f(x);   // v_exp_f32
}

// DPP-based add of lane^mask partner within each row of 16 (VALU pipe, not LDS).
template<int CTRL>
__device__ __forceinline__ float dpp_add(float v) {
    int m = __builtin_amdgcn_update_dpp(0, __float_as_int(v), CTRL, 0xF, 0xF, true);
    return v + __int_as_float(m);
}
// 16-lane sum (over lane bits 0..3): xor1, xor2 (quad_perm), then after quads are
// uniform, row_half_mirror (= +quad^1) and row_mirror (= +quad^3) complete the sum.
__device__ __forceinline__ float row16_sum(float v) {
    v = dpp_add<0xB1>(v);    // quad_perm [1,0,3,2]  : + lane^1
    v = dpp_add<0x4E>(v);    // quad_perm [2,3,0,1]  : + lane^2
    v = dpp_add<0x141>(v);   // row_half_mirror      : + other quad in half
    v = dpp_add<0x140>(v);   // row_mirror           : + other half of row
    return v;
}

// ================= merged prep kernel (slim LDS) =================
// grid 411: [0,128) GN1, [128,146) weight transpose, [146,154) temb MLP,
// [154,410) 1x1 conv, 410 = gstat zero (replaces hipMemsetAsync launch).
__global__ __launch_bounds__(256) void prep_kernel(
    const float* __restrict__ x, const float* __restrict__ gn1s,
    const float* __restrict__ gn1b, __bf16* __restrict__ aT,
    const float* __restrict__ c1w, const float* __restrict__ c2w,
    __bf16* __restrict__ wt,
    const float* __restrict__ t, const float* __restrict__ mlpw,
    const float* __restrict__ mlpb, float* __restrict__ tembw,
    const float* __restrict__ cond, const float* __restrict__ cw,
    const float* __restrict__ cb, __bf16* __restrict__ cmT,
    __bf16* __restrict__ cm2, float* __restrict__ gstat)
{
    __shared__ __align__(16) char pool[18432];
    __shared__ float rs[4], rs2[4], mean_s, inv_s;
    const int blk = blockIdx.x;
    const int tid = threadIdx.x;

    if (blk < 128) {
        // ---- GN1 two-pass ----
        const int b = blk >> 5, g = blk & 31;
        const float* p = x + (size_t)blk * 16384;
        float s = 0.f, s2 = 0.f;
        for (int it = 0; it < 16; ++it) {
            int q = it * 256 + tid;
            float4 v = *(const float4*)&p[q * 4];
            s += v.x + v.y + v.z + v.w;
            s2 += v.x * v.x + v.y * v.y + v.z * v.z + v.w * v.w;
        }
        #pragma unroll
        for (int off = 32; off >= 1; off >>= 1) {
            s  += __shfl_down(s,  off, 64);
            s2 += __shfl_down(s2, off, 64);
        }
        const int wid = tid >> 6;
        if ((tid & 63) == 0) { rs[wid] = s; rs2[wid] = s2; }
        __syncthreads();
        if (tid == 0) {
            float S = rs[0] + rs[1] + rs[2] + rs[3];
            float S2 = rs2[0] + rs2[1] + rs2[2] + rs2[3];
            float m = S * (1.f / 16384.f);
            float var = S2 * (1.f / 16384.f) - m * m;
            mean_s = m;
            inv_s = rsqrtf(var + 1e-5f);
        }
        __syncthreads();
        const float m = mean_s, inv = inv_s;
        float sc[4], bi[4];
        #pragma unroll
        for (int j = 0; j < 4; ++j) { sc[j] = gn1s[g * 4 + j]; bi[j] = gn1b[g * 4 + j]; }
        for (int it = 0; it < 16; ++it) {
            int pp = it * 256 + tid;
            bf16x4 o;
            #pragma unroll
            for (int j = 0; j < 4; ++j)
                o[j] = (__bf16)silu_f((p[j * 4096 + pp] - m) * inv * sc[j] + bi[j]);
            *(bf16x4*)&aT[((size_t)(b * SP + pp)) * CC + g * 4] = o;
        }
    } else if (blk < 146) {
        // ---- weight transpose ----
        const int idx = blk - 128;
        const int wsel = idx / 9, tap = idx % 9;
        const float* src = wsel ? c2w : c1w;
        __bf16* dst = wt + (size_t)wsel * 9 * 16384 + (size_t)tap * 16384;
        for (int it = 0; it < 64; ++it) {
            int q = it * 256 + tid;
            dst[q] = (__bf16)src[(size_t)q * 9 + tap];
        }
    } else if (blk < 154) {
        // ---- temb MLP ----
        const int cog = blk - 146;
        float* st = (float*)pool;
        for (int it = 0; it < 8; ++it) {
            int q = it * 256 + tid;
            st[q] = silu_f(t[q]);
        }
        __syncthreads();
        const int col = tid >> 4, seg = tid & 15;
        const float* wr = mlpw + (size_t)(cog * 16 + col) * 512 + seg * 32;
        float acc[4] = {0.f, 0.f, 0.f, 0.f};
        #pragma unroll
        for (int k8 = 0; k8 < 8; ++k8) {
            float4 wv = *(const float4*)&wr[k8 * 4];
            #pragma unroll
            for (int j = 0; j < 4; ++j) {
                int k = seg * 32 + k8 * 4 + j;
                float w4 = (&wv.x)[j];
                acc[0] += st[0 * 512 + k] * w4;
                acc[1] += st[1 * 512 + k] * w4;
                acc[2] += st[2 * 512 + k] * w4;
                acc[3] += st[3 * 512 + k] * w4;
            }
        }
        #pragma unroll
        for (int o = 1; o < 16; o <<= 1) {
            #pragma unroll
            for (int b4 = 0; b4 < 4; ++b4)
                acc[b4] += __shfl_xor(acc[b4], o, 64);
        }
        if (seg == 0) {
            float bv = mlpb[cog * 16 + col];
            #pragma unroll
            for (int b4 = 0; b4 < 4; ++b4)
                tembw[b4 * 128 + cog * 16 + col] = acc[b4] + bv;
        }
    } else if (blk < 410) {
        // ---- 1x1 conv MFMA ----
        const int pblk = blk - 154;
        const int b = pblk >> 6;
        const int p0 = (pblk & 63) * 64;
        const int l = tid & 63, wv = tid >> 6;
        const int l15 = l & 15, l4 = l >> 4;
        const int mB = wv * 32;

        __bf16* XT = (__bf16*)pool;

        for (int it = 0; it < 32; ++it) {
            int q = it * 256 + tid;
            float v = cond[((size_t)(b * CC + (q >> 6))) * SP + p0 + (q & 63)];
            XT[(q & 63) * 136 + (q >> 6)] = (__bf16)v;
        }
        __syncthreads();

        f32x4 acc[2][4];
        #pragma unroll
        for (int mb = 0; mb < 2; ++mb)
            #pragma unroll
            for (int nt = 0; nt < 4; ++nt) acc[mb][nt] = (f32x4){0.f, 0.f, 0.f, 0.f};

        #pragma unroll
        for (int ks = 0; ks < 4; ++ks) {
            bf16x8 bfr[4];
            #pragma unroll
            for (int nt = 0; nt < 4; ++nt)
                bfr[nt] = *(const bf16x8*)&XT[(nt * 16 + l15) * 136 + ks * 32 + l4 * 8];
            #pragma unroll
            for (int mb = 0; mb < 2; ++mb) {
                const float* wrow = cw + (size_t)(mB + mb * 16 + l15) * 128 + ks * 32 + l4 * 8;
                float4 wa = *(const float4*)wrow;
                float4 wb4 = *(const float4*)(wrow + 4);
                bf16x8 afr;
                afr[0] = (__bf16)wa.x; afr[1] = (__bf16)wa.y;
                afr[2] = (__bf16)wa.z; afr[3] = (__bf16)wa.w;
                afr[4] = (__bf16)wb4.x; afr[5] = (__bf16)wb4.y;
                afr[6] = (__bf16)wb4.z; afr[7] = (__bf16)wb4.w;
                #pragma unroll
                for (int nt = 0; nt < 4; ++nt)
                    acc[mb][nt] = __builtin_amdgcn_mfma_f32_16x16x32_bf16(afr, bfr[nt], acc[mb][nt], 0, 0, 0);
            }
        }

        // scale = log2(e)/sqrt(128): folds the softmax temperature AND the
        // exp->exp2 conversion into the attention K operand (cmT is only ever
        // consumed as the QK^T A-operand in attn_kernel).
        const float scl = 0.12751743f;
        #pragma unroll
        for (int mb = 0; mb < 2; ++mb) {
            int co0 = mB + mb * 16 + l4 * 4;
            float bv[4];
            #pragma unroll
            for (int r = 0; r < 4; ++r) bv[r] = cb[co0 + r];
            #pragma unroll
            for (int nt = 0; nt < 4; ++nt) {
                int p = p0 + nt * 16 + l15;
                bf16x4 o;
                #pragma unroll
                for (int r = 0; r < 4; ++r)
                    o[r] = (__bf16)((acc[mb][nt][r] + bv[r]) * scl);
                *(bf16x4*)&cmT[((size_t)(b * SP + p)) * CC + co0] = o;
            }
        }
        __syncthreads();
        __bf16* O2 = (__bf16*)pool;
        #pragma unroll
        for (int mb = 0; mb < 2; ++mb) {
            int co0 = mB + mb * 16 + l4 * 4;
            #pragma unroll
            for (int r = 0; r < 4; ++r) {
                float bv = cb[co0 + r];
                #pragma unroll
                for (int nt = 0; nt < 4; ++nt)
                    O2[(co0 + r) * 72 + nt * 16 + l15] = (__bf16)(acc[mb][nt][r] + bv);
            }
        }
        __syncthreads();
        #pragma unroll
        for (int it = 0; it < 4; ++it) {
            int q = it * 256 + tid;
            int co = q >> 3, pc = q & 7;
            *(bf16x8*)&cm2[((size_t)(b * CC + co)) * SP + p0 + pc * 8] =
                *(const bf16x8*)&O2[co * 72 + pc * 8];
        }
    } else {
        // ---- gstat zero (replaces memset launch) ----
        gstat[tid] = 0.f;
    }
}

// ---------------- 3x3 conv v2: 512-thread blocks, all 128 co per block ----------------
template<bool FUSE_TEMB, bool OUT_CF, bool FUSE_GN>
__global__ __launch_bounds__(512, 4) void conv_mfma_kernel(
    const __bf16* __restrict__ inT, const __bf16* __restrict__ wt,
    const float* __restrict__ bias, const float* __restrict__ temb,
    const float* __restrict__ resid, __bf16* __restrict__ outT,
    float* __restrict__ outF, const float* __restrict__ gstat,
    const float* __restrict__ gn_s, const float* __restrict__ gn_b)
{
    const int y   = blockIdx.x >> 1;
    const int xh2 = blockIdx.x & 1;
    const int x0  = xh2 * 32;
    const int b   = blockIdx.y;
    const int tid = threadIdx.x;
    const int l = tid & 63, wv = tid >> 6;
    const int l15 = l & 15, l4 = l >> 4;
    const int co_w = wv * 16;            // 8 waves -> co 0..127

    __shared__ __bf16 inS[3 * 16 * 34 * 8];   // 26 KB
    __shared__ float af[128], bfp[128];

    if (FUSE_GN) {
        if (tid < 128) {
            int g = tid >> 2;
            float S = gstat[(b * NG + g) * 2], S2 = gstat[(b * NG + g) * 2 + 1];
            float m = S * (1.f / 16384.f);
            float var = S2 * (1.f / 16384.f) - m * m;
            float inv = rsqrtf(var + 1e-5f);
            float a = inv * gn_s[tid];
            af[tid] = a;
            bfp[tid] = gn_b[tid] - m * a;
        }
        __syncthreads();
    }

    const __bf16* inTb = inT + (size_t)b * SP * CC;
    for (int q = tid; q < 3 * 34 * 16; q += 512) {
        int cc = q & 15;
        int t2 = q >> 4;
        int xs = t2 % 34;
        int r  = t2 / 34;
        int yy = y + r - 1;
        int xg = x0 + xs - 1;
        bf16x8 v;
        if (((unsigned)yy < 64u) && ((unsigned)xg < 64u)) {
            bf16x8 raw = *(const bf16x8*)&inTb[((size_t)(yy * 64 + xg)) * CC + cc * 8];
            if (FUSE_GN) {
                #pragma unroll
                for (int j = 0; j < 8; ++j) {
                    int c = cc * 8 + j;
                    v[j] = (__bf16)silu_f((float)raw[j] * af[c] + bfp[c]);
                }
            } else {
                v = raw;
            }
        } else {
            #pragma unroll
            for (int j = 0; j < 8; ++j) v[j] = (__bf16)0.f;
        }
        *(bf16x8*)&inS[((r * 16 + cc) * 34 + xs) * 8] = v;
    }
    __syncthreads();

    f32x4 acc[2];
    acc[0] = (f32x4){0.f, 0.f, 0.f, 0.f};
    acc[1] = (f32x4){0.f, 0.f, 0.f, 0.f};

    const __bf16* wp = wt + (size_t)(co_w + l15) * 128 + l4 * 8;
    bf16x8 wb[2][4];
    #pragma unroll
    for (int ks = 0; ks < 4; ++ks)
        wb[0][ks] = *(const bf16x8*)(wp + ks * 32);

    #pragma unroll
    for (int tap = 0; tap < 9; ++tap) {
        const int cur = tap & 1, nxt = cur ^ 1;
        if (tap < 8) {
            #pragma unroll
            for (int ks = 0; ks < 4; ++ks)
                wb[nxt][ks] = *(const bf16x8*)(wp + (tap + 1) * 16384 + ks * 32);
        }
        const int rr = tap / 3, dx = tap % 3;
        #pragma unroll
        for (int ks = 0; ks < 4; ++ks) {
            const __bf16* rb = &inS[((rr * 16 + ks * 4 + l4) * 34) * 8];
            bf16x8 b0 = *(const bf16x8*)&rb[(dx + l15) * 8];
            bf16x8 b1 = *(const bf16x8*)&rb[(16 + dx + l15) * 8];
            acc[0] = __builtin_amdgcn_mfma_f32_16x16x32_bf16(wb[cur][ks], b0, acc[0], 0, 0, 0);
            acc[1] = __builtin_amdgcn_mfma_f32_16x16x32_bf16(wb[cur][ks], b1, acc[1], 0, 0, 0);
        }
    }

    if (OUT_CF) {
        #pragma unroll
        for (int r = 0; r < 4; ++r) {
            int co = co_w + l4 * 4 + r;
            float bv = bias[co];
            #pragma unroll
            for (int nb = 0; nb < 2; ++nb) {
                int p = y * 64 + x0 + nb * 16 + l15;
                size_t o = ((size_t)(b * CC + co)) * SP + p;
                outF[o] = acc[nb][r] + bv + resid[o];
            }
        }
    } else {
        int co0 = co_w + l4 * 4;
        float bv[4];
        #pragma unroll
        for (int r = 0; r < 4; ++r)
            bv[r] = bias[co0 + r] + (FUSE_TEMB ? temb[b * CC + co0 + r] : 0.f);
        #pragma unroll
        for (int nb = 0; nb < 2; ++nb) {
            int p = y * 64 + x0 + nb * 16 + l15;
            bf16x4 o;
            #pragma unroll
            for (int r = 0; r < 4; ++r)
                o[r] = (__bf16)(acc[nb][r] + bv[r]);
            *(bf16x4*)&outT[((size_t)(b * SP + p)) * CC + co0] = o;
        }
    }
}

// ---------------- fused cross-attention v13 (REVERTED from v15's regression) ----------------
// v15 (2-tile windows) regressed 57.9->65.5us: producer's 2-tile chain is serial
// within a window and the post-B ct2b copy exposed HBM latency each window.
// v13 = proven best: producer/consumer wave split, code-motion K/V pipeline,
// XCD swizzle (FETCH 8.3MB, 57.9us, MfmaUtil 23.9%).
#define CT2 72    // ct2 row stride (bf16)
#define PBS 72    // Pb row stride (bf16)
// pool: ct2[2] 2x18432 B, Pb[2] 2x9216 B -> 55296 B
#define POOL_BYTES 55296
#define NIT (SP / TT / NS)   // 32

__global__ __launch_bounds__(512, 4) void attn_kernel(
    const __bf16* __restrict__ h1T, const __bf16* __restrict__ cmT,
    const __bf16* __restrict__ cm2, __bf16* __restrict__ parts)
{
    const int bid = blockIdx.x;
    const int w = bid >> 3;            // 64 values
    const int b = (bid >> 1) & 3;      // 4 values
    const int s = bid & 1;             // NS=2 values; (b,s) fixed per XCD
    const int tid = threadIdx.x;
    const int wid = tid >> 6;
    const int l = tid & 63, l15 = l & 15, l4 = l >> 4;

    __shared__ __align__(16) char pool[POOL_BYTES];
    __bf16* ct2p = (__bf16*)pool;               // 2 buffers of 9216 elems
    __bf16* Pbp  = (__bf16*)(pool + 36864);     // 2 buffers of 4608 elems
    __bf16* Otr  = (__bf16*)pool;               // epilogue alias

    const __bf16* h1Tb = h1T + (size_t)b * SP * CC;
    const __bf16* cmTb = cmT + (size_t)b * SP * CC;
    const __bf16* cm2b = cm2 + (size_t)b * CC * SP;

    if (wid < 4) {
        // ================= producer: QK^T + softmax =================
        const int pw = wid;   // owns 16 uv rows of each tile
        bf16x8 hfr[4][4];     // Q: 64h x 128c, register/AGPR-resident
        #pragma unroll
        for (int nt = 0; nt < 4; ++nt)
            #pragma unroll
            for (int ks = 0; ks < 4; ++ks)
                hfr[nt][ks] = *(const bf16x8*)&h1Tb[((size_t)((nt * 16 + l15) * WW + w)) * CC + ks * 32 + l4 * 8];

        bf16x8 afr[4];   // K fragments for the NEXT tile to produce

        // P(0) -> Pb[0], then issue K(1)
        {
            const int uv0 = s * TT;
            const __bf16* arow = cmTb + (size_t)(uv0 + 16 * pw + l15) * CC;
            bf16x8 a0[4];
            #pragma unroll
            for (int ks = 0; ks < 4; ++ks) a0[ks] = *(const bf16x8*)&arow[ks * 32 + l4 * 8];
            f32x4 s1[4];
            __builtin_amdgcn_s_setprio(1);
            #pragma unroll
            for (int nt = 0; nt < 4; ++nt) {
                s1[nt] = (f32x4){0.f, 0.f, 0.f, 0.f};
                #pragma unroll
                for (int ks = 0; ks < 4; ++ks)
                    s1[nt] = __builtin_amdgcn_mfma_f32_16x16x32_bf16(a0[ks], hfr[nt][ks], s1[nt], 0, 0, 0);
            }
            __builtin_amdgcn_s_setprio(0);
            // issue K(1) while softmax runs
            {
                const int uv1 = (NS + s) * TT;
                const __bf16* arow1 = cmTb + (size_t)(uv1 + 16 * pw + l15) * CC;
                #pragma unroll
                for (int ks = 0; ks < 4; ++ks) afr[ks] = *(const bf16x8*)&arow1[ks * 32 + l4 * 8];
            }
            #pragma unroll
            for (int r = 0; r < 4; ++r) {
                float e0 = fast_exp2(s1[0][r]), e1 = fast_exp2(s1[1][r]);
                float e2 = fast_exp2(s1[2][r]), e3 = fast_exp2(s1[3][r]);
                float sm = (e0 + e1) + (e2 + e3);
                sm = row16_sum(sm);
                float ri = 1.f / sm;
                s1[0][r] = e0 * ri; s1[1][r] = e1 * ri;
                s1[2][r] = e2 * ri; s1[3][r] = e3 * ri;
            }
            #pragma unroll
            for (int nt = 0; nt < 4; ++nt) {
                bf16x4 pk;
                pk[0] = (__bf16)s1[nt][0]; pk[1] = (__bf16)s1[nt][1];
                pk[2] = (__bf16)s1[nt][2]; pk[3] = (__bf16)s1[nt][3];
                *(bf16x4*)&Pbp[(nt * 16 + l15) * PBS + 16 * pw + l4 * 4] = pk;
            }
        }
        __syncthreads();   // #1: Pb[0] + ct2[0] ready

        for (int i = 0; i < NIT; ++i) {
            if (i < NIT - 1) {
                // afr holds K(i+1) (issued >= 1 iteration ago)
                f32x4 s1[4];
                __builtin_amdgcn_s_setprio(1);
                #pragma unroll
                for (int nt = 0; nt < 4; ++nt) {
                    s1[nt] = (f32x4){0.f, 0.f, 0.f, 0.f};
                    #pragma unroll
                    for (int ks = 0; ks < 4; ++ks)
                        s1[nt] = __builtin_amdgcn_mfma_f32_16x16x32_bf16(afr[ks], hfr[nt][ks], s1[nt], 0, 0, 0);
                }
                __builtin_amdgcn_s_setprio(0);
                // re-issue K(i+2) immediately after last use of afr
                if (i < NIT - 2) {
                    const int uv2 = ((i + 2) * NS + s) * TT;
                    const __bf16* arow = cmTb + (size_t)(uv2 + 16 * pw + l15) * CC;
                    #pragma unroll
                    for (int ks = 0; ks < 4; ++ks) afr[ks] = *(const bf16x8*)&arow[ks * 32 + l4 * 8];
                }
                #pragma unroll
                for (int r = 0; r < 4; ++r) {
                    float e0 = fast_exp2(s1[0][r]), e1 = fast_exp2(s1[1][r]);
                    float e2 = fast_exp2(s1[2][r]), e3 = fast_exp2(s1[3][r]);
                    float sm = (e0 + e1) + (e2 + e3);
                    sm = row16_sum(sm);
                    float ri = 1.f / sm;
                    s1[0][r] = e0 * ri; s1[1][r] = e1 * ri;
                    s1[2][r] = e2 * ri; s1[3][r] = e3 * ri;
                }
                __bf16* PbW = Pbp + ((i & 1) ^ 1) * 4608;
                #pragma unroll
                for (int nt = 0; nt < 4; ++nt) {
                    bf16x4 pk;
                    pk[0] = (__bf16)s1[nt][0]; pk[1] = (__bf16)s1[nt][1];
                    pk[2] = (__bf16)s1[nt][2]; pk[3] = (__bf16)s1[nt][3];
                    *(bf16x4*)&PbW[(nt * 16 + l15) * PBS + 16 * pw + l4 * 4] = pk;
                }
            }
            __syncthreads();   // per-iter barrier (matches consumer)
        }
    } else {
        // ================= consumer: PV accumulate =================
        const int cw = wid - 4;
        const int hB = (cw & 1) * 32;
        const int cB = (cw >> 1) * 64;
        const int tc = tid - 256;       // 0..255 within consumer group
        const int sc = tc >> 3;
        const int stc = tc & 7;

        f32x4 acc2[2][4];
        #pragma unroll
        for (int mb = 0; mb < 2; ++mb)
            #pragma unroll
            for (int nt = 0; nt < 4; ++nt) acc2[mb][nt] = (f32x4){0.f, 0.f, 0.f, 0.f};

        bf16x8 st4[4];   // V fragments for the NEXT tile to stage

        // stage ct2[0] directly, then issue V(1)
        {
            const int uv0 = s * TT;
            #pragma unroll
            for (int it = 0; it < 4; ++it) {
                int c = it * 32 + sc;
                *(bf16x8*)&ct2p[c * CT2 + stc * 8] =
                    *(const bf16x8*)&cm2b[(size_t)c * SP + uv0 + stc * 8];
            }
            const int uv1 = (NS + s) * TT;
            #pragma unroll
            for (int it = 0; it < 4; ++it) {
                int c = it * 32 + sc;
                st4[it] = *(const bf16x8*)&cm2b[(size_t)c * SP + uv1 + stc * 8];
            }
        }
        __syncthreads();   // #1: Pb[0] + ct2[0] ready

        for (int i = 0; i < NIT; ++i) {
            const int cur = i & 1;
            // consume tile i
            {
                const __bf16* PbR = Pbp + cur * 4608;
                const __bf16* ctR = ct2p + cur * 9216;
                bf16x8 pfr[2][2];
                #pragma unroll
                for (int mb = 0; mb < 2; ++mb)
                    #pragma unroll
                    for (int ks = 0; ks < 2; ++ks)
                        pfr[mb][ks] = *(const bf16x8*)&PbR[(hB + mb * 16 + l15) * PBS + ks * 32 + l4 * 8];
                bf16x8 bfr[4][2];
                #pragma unroll
                for (int nt = 0; nt < 4; ++nt)
                    #pragma unroll
                    for (int ks = 0; ks < 2; ++ks)
                        bfr[nt][ks] = *(const bf16x8*)&ctR[(cB + nt * 16 + l15) * CT2 + ks * 32 + l4 * 8];
                __builtin_amdgcn_s_setprio(1);
                #pragma unroll
                for (int mb = 0; mb < 2; ++mb)
                    #pragma unroll
                    for (int nt = 0; nt < 4; ++nt)
                        #pragma unroll
                        for (int ks = 0; ks < 2; ++ks)
                            acc2[mb][nt] = __builtin_amdgcn_mfma_f32_16x16x32_bf16(
                                pfr[mb][ks], bfr[nt][ks], acc2[mb][nt], 0, 0, 0);
                __builtin_amdgcn_s_setprio(0);
            }
            // write V(i+1) (in flight >= 1 iter) into the other LDS buffer,
            // then immediately issue V(i+2) into the drained st4 regs
            if (i < NIT - 1) {
                __bf16* ctW = ct2p + (cur ^ 1) * 9216;
                #pragma unroll
                for (int it = 0; it < 4; ++it) {
                    int c = it * 32 + sc;
                    *(bf16x8*)&ctW[c * CT2 + stc * 8] = st4[it];
                }
                if (i < NIT - 2) {
                    const int uv2 = ((i + 2) * NS + s) * TT;
                    #pragma unroll
                    for (int it = 0; it < 4; ++it) {
                        int c = it * 32 + sc;
                        st4[it] = *(const bf16x8*)&cm2b[(size_t)c * SP + uv2 + stc * 8];
                    }
                }
            }
            __syncthreads();   // per-iter barrier (matches producer)
        }

        // consumers hold the output: transpose-stage into LDS
        #pragma unroll
        for (int mb = 0; mb < 2; ++mb)
            #pragma unroll
            for (int nt = 0; nt < 4; ++nt)
                #pragma unroll
                for (int r = 0; r < 4; ++r)
                    Otr[(hB + mb * 16 + l4 * 4 + r) * 136 + cB + nt * 16 + l15] =
                        (__bf16)acc2[mb][nt][r];
    }

    __syncthreads();   // convergent: Otr complete
    __bf16* pO = parts + (size_t)s * PSZ;
    #pragma unroll
    for (int it = 0; it < 2; ++it) {
        int q = it * 512 + tid;
        int h = q >> 4, cc = q & 15;
        *(bf16x8*)&pO[((size_t)(b * SP + h * WW + w)) * CC + cc * 8] =
            *(const bf16x8*)&Otr[h * 136 + cc * 8];
    }
}

// ---------------- GN2 stats v2: bf16x8 loads, 2 blocks/CU ----------------
// Old: 256 blocks (1/CU), 8B loads, 8 iters/thread. New: 512 blocks (2/CU,
// 32 rows each), 16B loads, 2 iters/thread. Each thread owns 8 channels =
// exactly 2 groups; xor16/32 intra-wave reduce + LDS stage + 4 atomics/c8.
__global__ __launch_bounds__(256) void gn2_stats_kernel(
    const __bf16* __restrict__ h1T, const __bf16* __restrict__ parts,
    const int* __restrict__ aim, const float* __restrict__ emb,
    __bf16* __restrict__ h2T, float* __restrict__ gstat)
{
    const int pb = blockIdx.x, b = blockIdx.y;   // pb 0..127 (32 rows each)
    const int tid = threadIdx.x;
    const int c8 = tid & 15, rw = tid >> 4;      // channel octet / row-within-group
    const float4 ev0 = *(const float4*)&emb[aim[b] * CC + c8 * 8];
    const float4 ev1 = *(const float4*)&emb[aim[b] * CC + c8 * 8 + 4];
    float sa = 0.f, s2a = 0.f, sb = 0.f, s2b = 0.f;
    #pragma unroll
    for (int it = 0; it < 2; ++it) {
        int prow = pb * 32 + it * 16 + rw;
        size_t base = ((size_t)(b * SP + prow)) * CC + c8 * 8;
        bf16x8 hv = *(const bf16x8*)&h1T[base];
        bf16x8 a0 = *(const bf16x8*)&parts[base];
        bf16x8 a1 = *(const bf16x8*)&parts[PSZ + base];
        float v[8];
        #pragma unroll
        for (int j = 0; j < 4; ++j)
            v[j] = (float)hv[j] + (&ev0.x)[j] + (float)a0[j] + (float)a1[j];
        #pragma unroll
        for (int j = 4; j < 8; ++j)
            v[j] = (float)hv[j] + (&ev1.x)[j - 4] + (float)a0[j] + (float)a1[j];
        bf16x8 o;
        #pragma unroll
        for (int j = 0; j < 8; ++j) o[j] = (__bf16)v[j];
        *(bf16x8*)&h2T[base] = o;
        #pragma unroll
        for (int j = 0; j < 4; ++j) { sa += v[j]; s2a += v[j] * v[j]; }
        #pragma unroll
        for (int j = 4; j < 8; ++j) { sb += v[j]; s2b += v[j] * v[j]; }
    }
    // reduce across the 4 lanes in each wave sharing c8 (lane^16, lane^32)
    sa  += __shfl_xor(sa,  16, 64); sa  += __shfl_xor(sa,  32, 64);
    s2a += __shfl_xor(s2a, 16, 64); s2a += __shfl_xor(s2a, 32, 64);
    sb  += __shfl_xor(sb,  16, 64); sb  += __shfl_xor(sb,  32, 64);
    s2b += __shfl_xor(s2b, 16, 64); s2b += __shfl_xor(s2b, 32, 64);
    __shared__ float ls[4][16][4];
    const int wv = tid >> 6;
    if ((tid & 63) < 16) {
        ls[wv][c8][0] = sa;  ls[wv][c8][1] = s2a;
        ls[wv][c8][2] = sb;  ls[wv][c8][3] = s2b;
    }
    __syncthreads();
    if (tid < 16) {
        float A = 0.f, A2 = 0.f, Bs = 0.f, B2 = 0.f;
        #pragma unroll
        for (int v2 = 0; v2 < 4; ++v2) {
            A  += ls[v2][tid][0]; A2 += ls[v2][tid][1];
            Bs += ls[v2][tid][2]; B2 += ls[v2][tid][3];
        }
        atomicAdd(&gstat[(b * NG + tid * 2) * 2],     A);
        atomicAdd(&gstat[(b * NG + tid * 2) * 2 + 1], A2);
        atomicAdd(&gstat[(b * NG + tid * 2 + 1) * 2],     Bs);
        atomicAdd(&gstat[(b * NG + tid * 2 + 1) * 2 + 1], B2);
    }
}

extern "C" void kernel_launch(void* const* d_in, const int* in_sizes, int n_in,
                              void* d_out, int out_size, void* d_ws, size_t ws_size,
                              hipStream_t stream)
{
    const float* x     = (const float*)d_in[0];
    const float* t     = (const float*)d_in[1];
    const int*   aim   = (const int*)  d_in[2];
    const float* cond  = (const float*)d_in[3];
    const float* gn1s  = (const float*)d_in[4];
    const float* gn1b  = (const float*)d_in[5];
    const float* c1w   = (const float*)d_in[6];
    const float* c1b   = (const float*)d_in[7];
    const float* mlpw  = (const float*)d_in[8];
    const float* mlpb  = (const float*)d_in[9];
    const float* cw    = (const float*)d_in[10];
    const float* cb    = (const float*)d_in[11];
    const float* gn2s  = (const float*)d_in[12];
    const float* gn2b  = (const float*)d_in[13];
    const float* c2w   = (const float*)d_in[14];
    const float* c2b   = (const float*)d_in[15];
    const float* emb   = (const float*)d_in[16];
    float* out = (float*)d_out;
    float* ws = (float*)d_ws;

    // float-offset workspace map
    __bf16* aT    = (__bf16*)ws;                  // [0, 1048576)
    __bf16* h1T   = (__bf16*)(ws + 1048576);
    __bf16* cmT   = (__bf16*)(ws + 2097152);      // h2T after attn
    __bf16* cm2   = (__bf16*)(ws + 3145728);
    __bf16* parts = (__bf16*)(ws + 4194304);      // 2 partials
    __bf16* wt    = (__bf16*)(ws + 6291456);
    float*  tembw = ws + 6438912;
    float*  gstat = ws + 6439424;                 // 256 floats
    __bf16* h2T   = cmT;

    prep_kernel<<<dim3(411), dim3(256), 0, stream>>>(
        x, gn1s, gn1b, aT, c1w, c2w, wt, t, mlpw, mlpb, tembw,
        cond, cw, cb, cmT, cm2, gstat);
    conv_mfma_kernel<true, false, false><<<dim3(128, BB), dim3(512), 0, stream>>>(
        aT, wt, c1b, tembw, nullptr, h1T, nullptr, nullptr, nullptr, nullptr);
    attn_kernel<<<dim3(WW * BB * NS), dim3(512), 0, stream>>>(h1T, cmT, cm2, parts);
    gn2_stats_kernel<<<dim3(128, BB), dim3(256), 0, stream>>>(h1T, parts, aim, emb, h2T, gstat);
    conv_mfma_kernel<false, true, true><<<dim3(128, BB), dim3(512), 0, stream>>>(
        h2T, wt + (size_t)9 * 16384, c2b, nullptr, x, nullptr, out, gstat, gn2s, gn2b);
}

// Round 12
// 209.720 us; speedup vs baseline: 1.0273x; 1.0273x over previous
//
#include <hip/hip_runtime.h>
#include <cmath>

#define BB 4
#define CC 128
#define HH 64
#define WW 64
#define SP 4096   // H*W
#define NG 32     // groups
#define TT 64     // attention uv-tile width
#define NS 2      // attention uv split factor
#define PSZ ((size_t)BB * SP * CC)   // partial tensor elements

typedef __bf16 bf16x8 __attribute__((ext_vector_type(8)));
typedef __bf16 bf16x4 __attribute__((ext_vector_type(4)));
typedef float  f32x4  __attribute__((ext_vector_type(4)));

__device__ __forceinline__ float silu_f(float v) {
    return v / (1.f + __expf(-v));
}

__device__ __forceinline__ float fast_exp2(float x) {
    return exp2f(x);   // v_exp_f32
}

// DPP-based add of lane^mask partner within each row of 16 (VALU pipe, not LDS).
template<int CTRL>
__device__ __forceinline__ float dpp_add(float v) {
    int m = __builtin_amdgcn_update_dpp(0, __float_as_int(v), CTRL, 0xF, 0xF, true);
    return v + __int_as_float(m);
}
// 16-lane sum (over lane bits 0..3): xor1, xor2 (quad_perm), then after quads are
// uniform, row_half_mirror (= +quad^1) and row_mirror (= +quad^3) complete the sum.
__device__ __forceinline__ float row16_sum(float v) {
    v = dpp_add<0xB1>(v);    // quad_perm [1,0,3,2]  : + lane^1
    v = dpp_add<0x4E>(v);    // quad_perm [2,3,0,1]  : + lane^2
    v = dpp_add<0x141>(v);   // row_half_mirror      : + other quad in half
    v = dpp_add<0x140>(v);   // row_mirror           : + other half of row
    return v;
}

// ================= merged prep kernel (slim LDS) =================
// grid 411: [0,128) GN1, [128,146) weight transpose, [146,154) temb MLP,
// [154,410) 1x1 conv, 410 = gstat zero (replaces hipMemsetAsync launch).
__global__ __launch_bounds__(256) void prep_kernel(
    const float* __restrict__ x, const float* __restrict__ gn1s,
    const float* __restrict__ gn1b, __bf16* __restrict__ aT,
    const float* __restrict__ c1w, const float* __restrict__ c2w,
    __bf16* __restrict__ wt,
    const float* __restrict__ t, const float* __restrict__ mlpw,
    const float* __restrict__ mlpb, float* __restrict__ tembw,
    const float* __restrict__ cond, const float* __restrict__ cw,
    const float* __restrict__ cb, __bf16* __restrict__ cmT,
    __bf16* __restrict__ cm2, float* __restrict__ gstat)
{
    __shared__ __align__(16) char pool[18432];
    __shared__ float rs[4], rs2[4], mean_s, inv_s;
    const int blk = blockIdx.x;
    const int tid = threadIdx.x;

    if (blk < 128) {
        // ---- GN1 two-pass ----
        const int b = blk >> 5, g = blk & 31;
        const float* p = x + (size_t)blk * 16384;
        float s = 0.f, s2 = 0.f;
        for (int it = 0; it < 16; ++it) {
            int q = it * 256 + tid;
            float4 v = *(const float4*)&p[q * 4];
            s += v.x + v.y + v.z + v.w;
            s2 += v.x * v.x + v.y * v.y + v.z * v.z + v.w * v.w;
        }
        #pragma unroll
        for (int off = 32; off >= 1; off >>= 1) {
            s  += __shfl_down(s,  off, 64);
            s2 += __shfl_down(s2, off, 64);
        }
        const int wid = tid >> 6;
        if ((tid & 63) == 0) { rs[wid] = s; rs2[wid] = s2; }
        __syncthreads();
        if (tid == 0) {
            float S = rs[0] + rs[1] + rs[2] + rs[3];
            float S2 = rs2[0] + rs2[1] + rs2[2] + rs2[3];
            float m = S * (1.f / 16384.f);
            float var = S2 * (1.f / 16384.f) - m * m;
            mean_s = m;
            inv_s = rsqrtf(var + 1e-5f);
        }
        __syncthreads();
        const float m = mean_s, inv = inv_s;
        float sc[4], bi[4];
        #pragma unroll
        for (int j = 0; j < 4; ++j) { sc[j] = gn1s[g * 4 + j]; bi[j] = gn1b[g * 4 + j]; }
        for (int it = 0; it < 16; ++it) {
            int pp = it * 256 + tid;
            bf16x4 o;
            #pragma unroll
            for (int j = 0; j < 4; ++j)
                o[j] = (__bf16)silu_f((p[j * 4096 + pp] - m) * inv * sc[j] + bi[j]);
            *(bf16x4*)&aT[((size_t)(b * SP + pp)) * CC + g * 4] = o;
        }
    } else if (blk < 146) {
        // ---- weight transpose ----
        const int idx = blk - 128;
        const int wsel = idx / 9, tap = idx % 9;
        const float* src = wsel ? c2w : c1w;
        __bf16* dst = wt + (size_t)wsel * 9 * 16384 + (size_t)tap * 16384;
        for (int it = 0; it < 64; ++it) {
            int q = it * 256 + tid;
            dst[q] = (__bf16)src[(size_t)q * 9 + tap];
        }
    } else if (blk < 154) {
        // ---- temb MLP ----
        const int cog = blk - 146;
        float* st = (float*)pool;
        for (int it = 0; it < 8; ++it) {
            int q = it * 256 + tid;
            st[q] = silu_f(t[q]);
        }
        __syncthreads();
        const int col = tid >> 4, seg = tid & 15;
        const float* wr = mlpw + (size_t)(cog * 16 + col) * 512 + seg * 32;
        float acc[4] = {0.f, 0.f, 0.f, 0.f};
        #pragma unroll
        for (int k8 = 0; k8 < 8; ++k8) {
            float4 wv = *(const float4*)&wr[k8 * 4];
            #pragma unroll
            for (int j = 0; j < 4; ++j) {
                int k = seg * 32 + k8 * 4 + j;
                float w4 = (&wv.x)[j];
                acc[0] += st[0 * 512 + k] * w4;
                acc[1] += st[1 * 512 + k] * w4;
                acc[2] += st[2 * 512 + k] * w4;
                acc[3] += st[3 * 512 + k] * w4;
            }
        }
        #pragma unroll
        for (int o = 1; o < 16; o <<= 1) {
            #pragma unroll
            for (int b4 = 0; b4 < 4; ++b4)
                acc[b4] += __shfl_xor(acc[b4], o, 64);
        }
        if (seg == 0) {
            float bv = mlpb[cog * 16 + col];
            #pragma unroll
            for (int b4 = 0; b4 < 4; ++b4)
                tembw[b4 * 128 + cog * 16 + col] = acc[b4] + bv;
        }
    } else if (blk < 410) {
        // ---- 1x1 conv MFMA ----
        const int pblk = blk - 154;
        const int b = pblk >> 6;
        const int p0 = (pblk & 63) * 64;
        const int l = tid & 63, wv = tid >> 6;
        const int l15 = l & 15, l4 = l >> 4;
        const int mB = wv * 32;

        __bf16* XT = (__bf16*)pool;

        for (int it = 0; it < 32; ++it) {
            int q = it * 256 + tid;
            float v = cond[((size_t)(b * CC + (q >> 6))) * SP + p0 + (q & 63)];
            XT[(q & 63) * 136 + (q >> 6)] = (__bf16)v;
        }
        __syncthreads();

        f32x4 acc[2][4];
        #pragma unroll
        for (int mb = 0; mb < 2; ++mb)
            #pragma unroll
            for (int nt = 0; nt < 4; ++nt) acc[mb][nt] = (f32x4){0.f, 0.f, 0.f, 0.f};

        #pragma unroll
        for (int ks = 0; ks < 4; ++ks) {
            bf16x8 bfr[4];
            #pragma unroll
            for (int nt = 0; nt < 4; ++nt)
                bfr[nt] = *(const bf16x8*)&XT[(nt * 16 + l15) * 136 + ks * 32 + l4 * 8];
            #pragma unroll
            for (int mb = 0; mb < 2; ++mb) {
                const float* wrow = cw + (size_t)(mB + mb * 16 + l15) * 128 + ks * 32 + l4 * 8;
                float4 wa = *(const float4*)wrow;
                float4 wb4 = *(const float4*)(wrow + 4);
                bf16x8 afr;
                afr[0] = (__bf16)wa.x; afr[1] = (__bf16)wa.y;
                afr[2] = (__bf16)wa.z; afr[3] = (__bf16)wa.w;
                afr[4] = (__bf16)wb4.x; afr[5] = (__bf16)wb4.y;
                afr[6] = (__bf16)wb4.z; afr[7] = (__bf16)wb4.w;
                #pragma unroll
                for (int nt = 0; nt < 4; ++nt)
                    acc[mb][nt] = __builtin_amdgcn_mfma_f32_16x16x32_bf16(afr, bfr[nt], acc[mb][nt], 0, 0, 0);
            }
        }

        // scale = log2(e)/sqrt(128): folds the softmax temperature AND the
        // exp->exp2 conversion into the attention K operand (cmT is only ever
        // consumed as the QK^T A-operand in attn_kernel).
        const float scl = 0.12751743f;
        #pragma unroll
        for (int mb = 0; mb < 2; ++mb) {
            int co0 = mB + mb * 16 + l4 * 4;
            float bv[4];
            #pragma unroll
            for (int r = 0; r < 4; ++r) bv[r] = cb[co0 + r];
            #pragma unroll
            for (int nt = 0; nt < 4; ++nt) {
                int p = p0 + nt * 16 + l15;
                bf16x4 o;
                #pragma unroll
                for (int r = 0; r < 4; ++r)
                    o[r] = (__bf16)((acc[mb][nt][r] + bv[r]) * scl);
                *(bf16x4*)&cmT[((size_t)(b * SP + p)) * CC + co0] = o;
            }
        }
        __syncthreads();
        __bf16* O2 = (__bf16*)pool;
        #pragma unroll
        for (int mb = 0; mb < 2; ++mb) {
            int co0 = mB + mb * 16 + l4 * 4;
            #pragma unroll
            for (int r = 0; r < 4; ++r) {
                float bv = cb[co0 + r];
                #pragma unroll
                for (int nt = 0; nt < 4; ++nt)
                    O2[(co0 + r) * 72 + nt * 16 + l15] = (__bf16)(acc[mb][nt][r] + bv);
            }
        }
        __syncthreads();
        #pragma unroll
        for (int it = 0; it < 4; ++it) {
            int q = it * 256 + tid;
            int co = q >> 3, pc = q & 7;
            *(bf16x8*)&cm2[((size_t)(b * CC + co)) * SP + p0 + pc * 8] =
                *(const bf16x8*)&O2[co * 72 + pc * 8];
        }
    } else {
        // ---- gstat zero (replaces memset launch) ----
        gstat[tid] = 0.f;
    }
}

// ---------------- 3x3 conv v2: 512-thread blocks, all 128 co per block ----------------
template<bool FUSE_TEMB, bool OUT_CF, bool FUSE_GN>
__global__ __launch_bounds__(512, 4) void conv_mfma_kernel(
    const __bf16* __restrict__ inT, const __bf16* __restrict__ wt,
    const float* __restrict__ bias, const float* __restrict__ temb,
    const float* __restrict__ resid, __bf16* __restrict__ outT,
    float* __restrict__ outF, const float* __restrict__ gstat,
    const float* __restrict__ gn_s, const float* __restrict__ gn_b)
{
    const int y   = blockIdx.x >> 1;
    const int xh2 = blockIdx.x & 1;
    const int x0  = xh2 * 32;
    const int b   = blockIdx.y;
    const int tid = threadIdx.x;
    const int l = tid & 63, wv = tid >> 6;
    const int l15 = l & 15, l4 = l >> 4;
    const int co_w = wv * 16;            // 8 waves -> co 0..127

    __shared__ __bf16 inS[3 * 16 * 34 * 8];   // 26 KB
    __shared__ float af[128], bfp[128];

    if (FUSE_GN) {
        if (tid < 128) {
            int g = tid >> 2;
            float S = gstat[(b * NG + g) * 2], S2 = gstat[(b * NG + g) * 2 + 1];
            float m = S * (1.f / 16384.f);
            float var = S2 * (1.f / 16384.f) - m * m;
            float inv = rsqrtf(var + 1e-5f);
            float a = inv * gn_s[tid];
            af[tid] = a;
            bfp[tid] = gn_b[tid] - m * a;
        }
        __syncthreads();
    }

    const __bf16* inTb = inT + (size_t)b * SP * CC;
    for (int q = tid; q < 3 * 34 * 16; q += 512) {
        int cc = q & 15;
        int t2 = q >> 4;
        int xs = t2 % 34;
        int r  = t2 / 34;
        int yy = y + r - 1;
        int xg = x0 + xs - 1;
        bf16x8 v;
        if (((unsigned)yy < 64u) && ((unsigned)xg < 64u)) {
            bf16x8 raw = *(const bf16x8*)&inTb[((size_t)(yy * 64 + xg)) * CC + cc * 8];
            if (FUSE_GN) {
                #pragma unroll
                for (int j = 0; j < 8; ++j) {
                    int c = cc * 8 + j;
                    v[j] = (__bf16)silu_f((float)raw[j] * af[c] + bfp[c]);
                }
            } else {
                v = raw;
            }
        } else {
            #pragma unroll
            for (int j = 0; j < 8; ++j) v[j] = (__bf16)0.f;
        }
        *(bf16x8*)&inS[((r * 16 + cc) * 34 + xs) * 8] = v;
    }
    __syncthreads();

    f32x4 acc[2];
    acc[0] = (f32x4){0.f, 0.f, 0.f, 0.f};
    acc[1] = (f32x4){0.f, 0.f, 0.f, 0.f};

    const __bf16* wp = wt + (size_t)(co_w + l15) * 128 + l4 * 8;
    bf16x8 wb[2][4];
    #pragma unroll
    for (int ks = 0; ks < 4; ++ks)
        wb[0][ks] = *(const bf16x8*)(wp + ks * 32);

    #pragma unroll
    for (int tap = 0; tap < 9; ++tap) {
        const int cur = tap & 1, nxt = cur ^ 1;
        if (tap < 8) {
            #pragma unroll
            for (int ks = 0; ks < 4; ++ks)
                wb[nxt][ks] = *(const bf16x8*)(wp + (tap + 1) * 16384 + ks * 32);
        }
        const int rr = tap / 3, dx = tap % 3;
        #pragma unroll
        for (int ks = 0; ks < 4; ++ks) {
            const __bf16* rb = &inS[((rr * 16 + ks * 4 + l4) * 34) * 8];
            bf16x8 b0 = *(const bf16x8*)&rb[(dx + l15) * 8];
            bf16x8 b1 = *(const bf16x8*)&rb[(16 + dx + l15) * 8];
            acc[0] = __builtin_amdgcn_mfma_f32_16x16x32_bf16(wb[cur][ks], b0, acc[0], 0, 0, 0);
            acc[1] = __builtin_amdgcn_mfma_f32_16x16x32_bf16(wb[cur][ks], b1, acc[1], 0, 0, 0);
        }
    }

    if (OUT_CF) {
        #pragma unroll
        for (int r = 0; r < 4; ++r) {
            int co = co_w + l4 * 4 + r;
            float bv = bias[co];
            #pragma unroll
            for (int nb = 0; nb < 2; ++nb) {
                int p = y * 64 + x0 + nb * 16 + l15;
                size_t o = ((size_t)(b * CC + co)) * SP + p;
                outF[o] = acc[nb][r] + bv + resid[o];
            }
        }
    } else {
        int co0 = co_w + l4 * 4;
        float bv[4];
        #pragma unroll
        for (int r = 0; r < 4; ++r)
            bv[r] = bias[co0 + r] + (FUSE_TEMB ? temb[b * CC + co0 + r] : 0.f);
        #pragma unroll
        for (int nb = 0; nb < 2; ++nb) {
            int p = y * 64 + x0 + nb * 16 + l15;
            bf16x4 o;
            #pragma unroll
            for (int r = 0; r < 4; ++r)
                o[r] = (__bf16)(acc[nb][r] + bv[r]);
            *(bf16x4*)&outT[((size_t)(b * SP + p)) * CC + co0] = o;
        }
    }
}

// ---------------- fused cross-attention v13 (proven best: 57.9us) ----------------
// producer/consumer wave split, code-motion K/V pipeline, XCD swizzle.
#define CT2 72    // ct2 row stride (bf16)
#define PBS 72    // Pb row stride (bf16)
// pool: ct2[2] 2x18432 B, Pb[2] 2x9216 B -> 55296 B
#define POOL_BYTES 55296
#define NIT (SP / TT / NS)   // 32

__global__ __launch_bounds__(512, 4) void attn_kernel(
    const __bf16* __restrict__ h1T, const __bf16* __restrict__ cmT,
    const __bf16* __restrict__ cm2, __bf16* __restrict__ parts)
{
    const int bid = blockIdx.x;
    const int w = bid >> 3;            // 64 values
    const int b = (bid >> 1) & 3;      // 4 values
    const int s = bid & 1;             // NS=2 values; (b,s) fixed per XCD
    const int tid = threadIdx.x;
    const int wid = tid >> 6;
    const int l = tid & 63, l15 = l & 15, l4 = l >> 4;

    __shared__ __align__(16) char pool[POOL_BYTES];
    __bf16* ct2p = (__bf16*)pool;               // 2 buffers of 9216 elems
    __bf16* Pbp  = (__bf16*)(pool + 36864);     // 2 buffers of 4608 elems
    __bf16* Otr  = (__bf16*)pool;               // epilogue alias

    const __bf16* h1Tb = h1T + (size_t)b * SP * CC;
    const __bf16* cmTb = cmT + (size_t)b * SP * CC;
    const __bf16* cm2b = cm2 + (size_t)b * CC * SP;

    if (wid < 4) {
        // ================= producer: QK^T + softmax =================
        const int pw = wid;   // owns 16 uv rows of each tile
        bf16x8 hfr[4][4];     // Q: 64h x 128c, register/AGPR-resident
        #pragma unroll
        for (int nt = 0; nt < 4; ++nt)
            #pragma unroll
            for (int ks = 0; ks < 4; ++ks)
                hfr[nt][ks] = *(const bf16x8*)&h1Tb[((size_t)((nt * 16 + l15) * WW + w)) * CC + ks * 32 + l4 * 8];

        bf16x8 afr[4];   // K fragments for the NEXT tile to produce

        // P(0) -> Pb[0], then issue K(1)
        {
            const int uv0 = s * TT;
            const __bf16* arow = cmTb + (size_t)(uv0 + 16 * pw + l15) * CC;
            bf16x8 a0[4];
            #pragma unroll
            for (int ks = 0; ks < 4; ++ks) a0[ks] = *(const bf16x8*)&arow[ks * 32 + l4 * 8];
            f32x4 s1[4];
            __builtin_amdgcn_s_setprio(1);
            #pragma unroll
            for (int nt = 0; nt < 4; ++nt) {
                s1[nt] = (f32x4){0.f, 0.f, 0.f, 0.f};
                #pragma unroll
                for (int ks = 0; ks < 4; ++ks)
                    s1[nt] = __builtin_amdgcn_mfma_f32_16x16x32_bf16(a0[ks], hfr[nt][ks], s1[nt], 0, 0, 0);
            }
            __builtin_amdgcn_s_setprio(0);
            // issue K(1) while softmax runs
            {
                const int uv1 = (NS + s) * TT;
                const __bf16* arow1 = cmTb + (size_t)(uv1 + 16 * pw + l15) * CC;
                #pragma unroll
                for (int ks = 0; ks < 4; ++ks) afr[ks] = *(const bf16x8*)&arow1[ks * 32 + l4 * 8];
            }
            #pragma unroll
            for (int r = 0; r < 4; ++r) {
                float e0 = fast_exp2(s1[0][r]), e1 = fast_exp2(s1[1][r]);
                float e2 = fast_exp2(s1[2][r]), e3 = fast_exp2(s1[3][r]);
                float sm = (e0 + e1) + (e2 + e3);
                sm = row16_sum(sm);
                float ri = 1.f / sm;
                s1[0][r] = e0 * ri; s1[1][r] = e1 * ri;
                s1[2][r] = e2 * ri; s1[3][r] = e3 * ri;
            }
            #pragma unroll
            for (int nt = 0; nt < 4; ++nt) {
                bf16x4 pk;
                pk[0] = (__bf16)s1[nt][0]; pk[1] = (__bf16)s1[nt][1];
                pk[2] = (__bf16)s1[nt][2]; pk[3] = (__bf16)s1[nt][3];
                *(bf16x4*)&Pbp[(nt * 16 + l15) * PBS + 16 * pw + l4 * 4] = pk;
            }
        }
        __syncthreads();   // #1: Pb[0] + ct2[0] ready

        for (int i = 0; i < NIT; ++i) {
            if (i < NIT - 1) {
                // afr holds K(i+1) (issued >= 1 iteration ago)
                f32x4 s1[4];
                __builtin_amdgcn_s_setprio(1);
                #pragma unroll
                for (int nt = 0; nt < 4; ++nt) {
                    s1[nt] = (f32x4){0.f, 0.f, 0.f, 0.f};
                    #pragma unroll
                    for (int ks = 0; ks < 4; ++ks)
                        s1[nt] = __builtin_amdgcn_mfma_f32_16x16x32_bf16(afr[ks], hfr[nt][ks], s1[nt], 0, 0, 0);
                }
                __builtin_amdgcn_s_setprio(0);
                // re-issue K(i+2) immediately after last use of afr
                if (i < NIT - 2) {
                    const int uv2 = ((i + 2) * NS + s) * TT;
                    const __bf16* arow = cmTb + (size_t)(uv2 + 16 * pw + l15) * CC;
                    #pragma unroll
                    for (int ks = 0; ks < 4; ++ks) afr[ks] = *(const bf16x8*)&arow[ks * 32 + l4 * 8];
                }
                #pragma unroll
                for (int r = 0; r < 4; ++r) {
                    float e0 = fast_exp2(s1[0][r]), e1 = fast_exp2(s1[1][r]);
                    float e2 = fast_exp2(s1[2][r]), e3 = fast_exp2(s1[3][r]);
                    float sm = (e0 + e1) + (e2 + e3);
                    sm = row16_sum(sm);
                    float ri = 1.f / sm;
                    s1[0][r] = e0 * ri; s1[1][r] = e1 * ri;
                    s1[2][r] = e2 * ri; s1[3][r] = e3 * ri;
                }
                __bf16* PbW = Pbp + ((i & 1) ^ 1) * 4608;
                #pragma unroll
                for (int nt = 0; nt < 4; ++nt) {
                    bf16x4 pk;
                    pk[0] = (__bf16)s1[nt][0]; pk[1] = (__bf16)s1[nt][1];
                    pk[2] = (__bf16)s1[nt][2]; pk[3] = (__bf16)s1[nt][3];
                    *(bf16x4*)&PbW[(nt * 16 + l15) * PBS + 16 * pw + l4 * 4] = pk;
                }
            }
            __syncthreads();   // per-iter barrier (matches consumer)
        }
    } else {
        // ================= consumer: PV accumulate =================
        const int cw = wid - 4;
        const int hB = (cw & 1) * 32;
        const int cB = (cw >> 1) * 64;
        const int tc = tid - 256;       // 0..255 within consumer group
        const int sc = tc >> 3;
        const int stc = tc & 7;

        f32x4 acc2[2][4];
        #pragma unroll
        for (int mb = 0; mb < 2; ++mb)
            #pragma unroll
            for (int nt = 0; nt < 4; ++nt) acc2[mb][nt] = (f32x4){0.f, 0.f, 0.f, 0.f};

        bf16x8 st4[4];   // V fragments for the NEXT tile to stage

        // stage ct2[0] directly, then issue V(1)
        {
            const int uv0 = s * TT;
            #pragma unroll
            for (int it = 0; it < 4; ++it) {
                int c = it * 32 + sc;
                *(bf16x8*)&ct2p[c * CT2 + stc * 8] =
                    *(const bf16x8*)&cm2b[(size_t)c * SP + uv0 + stc * 8];
            }
            const int uv1 = (NS + s) * TT;
            #pragma unroll
            for (int it = 0; it < 4; ++it) {
                int c = it * 32 + sc;
                st4[it] = *(const bf16x8*)&cm2b[(size_t)c * SP + uv1 + stc * 8];
            }
        }
        __syncthreads();   // #1: Pb[0] + ct2[0] ready

        for (int i = 0; i < NIT; ++i) {
            const int cur = i & 1;
            // consume tile i
            {
                const __bf16* PbR = Pbp + cur * 4608;
                const __bf16* ctR = ct2p + cur * 9216;
                bf16x8 pfr[2][2];
                #pragma unroll
                for (int mb = 0; mb < 2; ++mb)
                    #pragma unroll
                    for (int ks = 0; ks < 2; ++ks)
                        pfr[mb][ks] = *(const bf16x8*)&PbR[(hB + mb * 16 + l15) * PBS + ks * 32 + l4 * 8];
                bf16x8 bfr[4][2];
                #pragma unroll
                for (int nt = 0; nt < 4; ++nt)
                    #pragma unroll
                    for (int ks = 0; ks < 2; ++ks)
                        bfr[nt][ks] = *(const bf16x8*)&ctR[(cB + nt * 16 + l15) * CT2 + ks * 32 + l4 * 8];
                __builtin_amdgcn_s_setprio(1);
                #pragma unroll
                for (int mb = 0; mb < 2; ++mb)
                    #pragma unroll
                    for (int nt = 0; nt < 4; ++nt)
                        #pragma unroll
                        for (int ks = 0; ks < 2; ++ks)
                            acc2[mb][nt] = __builtin_amdgcn_mfma_f32_16x16x32_bf16(
                                pfr[mb][ks], bfr[nt][ks], acc2[mb][nt], 0, 0, 0);
                __builtin_amdgcn_s_setprio(0);
            }
            // write V(i+1) (in flight >= 1 iter) into the other LDS buffer,
            // then immediately issue V(i+2) into the drained st4 regs
            if (i < NIT - 1) {
                __bf16* ctW = ct2p + (cur ^ 1) * 9216;
                #pragma unroll
                for (int it = 0; it < 4; ++it) {
                    int c = it * 32 + sc;
                    *(bf16x8*)&ctW[c * CT2 + stc * 8] = st4[it];
                }
                if (i < NIT - 2) {
                    const int uv2 = ((i + 2) * NS + s) * TT;
                    #pragma unroll
                    for (int it = 0; it < 4; ++it) {
                        int c = it * 32 + sc;
                        st4[it] = *(const bf16x8*)&cm2b[(size_t)c * SP + uv2 + stc * 8];
                    }
                }
            }
            __syncthreads();   // per-iter barrier (matches producer)
        }

        // consumers hold the output: transpose-stage into LDS
        #pragma unroll
        for (int mb = 0; mb < 2; ++mb)
            #pragma unroll
            for (int nt = 0; nt < 4; ++nt)
                #pragma unroll
                for (int r = 0; r < 4; ++r)
                    Otr[(hB + mb * 16 + l4 * 4 + r) * 136 + cB + nt * 16 + l15] =
                        (__bf16)acc2[mb][nt][r];
    }

    __syncthreads();   // convergent: Otr complete
    __bf16* pO = parts + (size_t)s * PSZ;
    #pragma unroll
    for (int it = 0; it < 2; ++it) {
        int q = it * 512 + tid;
        int h = q >> 4, cc = q & 15;
        *(bf16x8*)&pO[((size_t)(b * SP + h * WW + w)) * CC + cc * 8] =
            *(const bf16x8*)&Otr[h * 136 + cc * 8];
    }
}

// ---------------- GN2 stats v1 (REVERTED from v2's regression) ----------------
// v2 (bf16x8 + 512 blocks) coincided with +6.4us total vs round 9; restore the
// proven grid (64,BB) / bf16x4 structure.
__global__ __launch_bounds__(256) void gn2_stats_kernel(
    const __bf16* __restrict__ h1T, const __bf16* __restrict__ parts,
    const int* __restrict__ aim, const float* __restrict__ emb,
    __bf16* __restrict__ h2T, float* __restrict__ gstat)
{
    const int pb = blockIdx.x, b = blockIdx.y;
    const int tid = threadIdx.x;
    const int c4 = tid & 31;
    const float4 ev = *(const float4*)&emb[aim[b] * CC + c4 * 4];
    float s = 0.f, s2 = 0.f;
    for (int it = 0; it < 8; ++it) {
        int prow = it * 8 + (tid >> 5);
        size_t base = ((size_t)(b * SP + pb * 64 + prow)) * CC + c4 * 4;
        bf16x4 hv = *(const bf16x4*)&h1T[base];
        float v0 = (float)hv[0] + ev.x;
        float v1 = (float)hv[1] + ev.y;
        float v2 = (float)hv[2] + ev.z;
        float v3 = (float)hv[3] + ev.w;
        #pragma unroll
        for (int k = 0; k < NS; ++k) {
            bf16x4 a = *(const bf16x4*)&parts[(size_t)k * PSZ + base];
            v0 += (float)a[0]; v1 += (float)a[1];
            v2 += (float)a[2]; v3 += (float)a[3];
        }
        bf16x4 o;
        o[0] = (__bf16)v0; o[1] = (__bf16)v1;
        o[2] = (__bf16)v2; o[3] = (__bf16)v3;
        *(bf16x4*)&h2T[base] = o;
        s += v0 + v1 + v2 + v3;
        s2 += v0 * v0 + v1 * v1 + v2 * v2 + v3 * v3;
    }
    s  += __shfl_down(s,  32, 64);
    s2 += __shfl_down(s2, 32, 64);
    __shared__ float ls[4][32][2];
    const int wv = tid >> 6, ll = tid & 63;
    if (ll < 32) { ls[wv][ll][0] = s; ls[wv][ll][1] = s2; }
    __syncthreads();
    if (tid < 32) {
        float S = ls[0][tid][0] + ls[1][tid][0] + ls[2][tid][0] + ls[3][tid][0];
        float S2 = ls[0][tid][1] + ls[1][tid][1] + ls[2][tid][1] + ls[3][tid][1];
        atomicAdd(&gstat[(b * NG + tid) * 2], S);
        atomicAdd(&gstat[(b * NG + tid) * 2 + 1], S2);
    }
}

extern "C" void kernel_launch(void* const* d_in, const int* in_sizes, int n_in,
                              void* d_out, int out_size, void* d_ws, size_t ws_size,
                              hipStream_t stream)
{
    const float* x     = (const float*)d_in[0];
    const float* t     = (const float*)d_in[1];
    const int*   aim   = (const int*)  d_in[2];
    const float* cond  = (const float*)d_in[3];
    const float* gn1s  = (const float*)d_in[4];
    const float* gn1b  = (const float*)d_in[5];
    const float* c1w   = (const float*)d_in[6];
    const float* c1b   = (const float*)d_in[7];
    const float* mlpw  = (const float*)d_in[8];
    const float* mlpb  = (const float*)d_in[9];
    const float* cw    = (const float*)d_in[10];
    const float* cb    = (const float*)d_in[11];
    const float* gn2s  = (const float*)d_in[12];
    const float* gn2b  = (const float*)d_in[13];
    const float* c2w   = (const float*)d_in[14];
    const float* c2b   = (const float*)d_in[15];
    const float* emb   = (const float*)d_in[16];
    float* out = (float*)d_out;
    float* ws = (float*)d_ws;

    // float-offset workspace map
    __bf16* aT    = (__bf16*)ws;                  // [0, 1048576)
    __bf16* h1T   = (__bf16*)(ws + 1048576);
    __bf16* cmT   = (__bf16*)(ws + 2097152);      // h2T after attn
    __bf16* cm2   = (__bf16*)(ws + 3145728);
    __bf16* parts = (__bf16*)(ws + 4194304);      // 2 partials
    __bf16* wt    = (__bf16*)(ws + 6291456);
    float*  tembw = ws + 6438912;
    float*  gstat = ws + 6439424;                 // 256 floats
    __bf16* h2T   = cmT;

    prep_kernel<<<dim3(411), dim3(256), 0, stream>>>(
        x, gn1s, gn1b, aT, c1w, c2w, wt, t, mlpw, mlpb, tembw,
        cond, cw, cb, cmT, cm2, gstat);
    conv_mfma_kernel<true, false, false><<<dim3(128, BB), dim3(512), 0, stream>>>(
        aT, wt, c1b, tembw, nullptr, h1T, nullptr, nullptr, nullptr, nullptr);
    attn_kernel<<<dim3(WW * BB * NS), dim3(512), 0, stream>>>(h1T, cmT, cm2, parts);
    gn2_stats_kernel<<<dim3(64, BB), dim3(256), 0, stream>>>(h1T, parts, aim, emb, h2T, gstat);
    conv_mfma_kernel<false, true, true><<<dim3(128, BB), dim3(512), 0, stream>>>(
        h2T, wt + (size_t)9 * 16384, c2b, nullptr, x, nullptr, out, gstat, gn2s, gn2b);
}

// Round 13
// 199.391 us; speedup vs baseline: 1.0805x; 1.0518x over previous
//
#include <hip/hip_runtime.h>
#include <cmath>

#define BB 4
#define CC 128
#define HH 64
#define WW 64
#define SP 4096   // H*W
#define NG 32     // groups
#define TT 64     // attention uv-tile width
#define NS 2      // attention uv split factor
#define PSZ ((size_t)BB * SP * CC)   // partial tensor elements

typedef __bf16 bf16x8 __attribute__((ext_vector_type(8)));
typedef __bf16 bf16x4 __attribute__((ext_vector_type(4)));
typedef float  f32x4  __attribute__((ext_vector_type(4)));

__device__ __forceinline__ float silu_f(float v) {
    return v / (1.f + __expf(-v));
}

__device__ __forceinline__ float fast_exp2(float x) {
    return exp2f(x);   // v_exp_f32
}

// DPP-based add of lane^mask partner within each row of 16 (VALU pipe, not LDS).
template<int CTRL>
__device__ __forceinline__ float dpp_add(float v) {
    int m = __builtin_amdgcn_update_dpp(0, __float_as_int(v), CTRL, 0xF, 0xF, true);
    return v + __int_as_float(m);
}
// 16-lane sum (over lane bits 0..3): xor1, xor2 (quad_perm), then after quads are
// uniform, row_half_mirror (= +quad^1) and row_mirror (= +quad^3) complete the sum.
__device__ __forceinline__ float row16_sum(float v) {
    v = dpp_add<0xB1>(v);    // quad_perm [1,0,3,2]  : + lane^1
    v = dpp_add<0x4E>(v);    // quad_perm [2,3,0,1]  : + lane^2
    v = dpp_add<0x141>(v);   // row_half_mirror      : + other quad in half
    v = dpp_add<0x140>(v);   // row_mirror           : + other half of row
    return v;
}

// ================= merged prep kernel (slim LDS) =================
// grid 411: [0,128) GN1, [128,146) weight transpose, [146,154) temb MLP,
// [154,410) 1x1 conv, 410 = gstat zero (replaces hipMemsetAsync launch).
__global__ __launch_bounds__(256) void prep_kernel(
    const float* __restrict__ x, const float* __restrict__ gn1s,
    const float* __restrict__ gn1b, __bf16* __restrict__ aT,
    const float* __restrict__ c1w, const float* __restrict__ c2w,
    __bf16* __restrict__ wt,
    const float* __restrict__ t, const float* __restrict__ mlpw,
    const float* __restrict__ mlpb, float* __restrict__ tembw,
    const float* __restrict__ cond, const float* __restrict__ cw,
    const float* __restrict__ cb, __bf16* __restrict__ cmT,
    __bf16* __restrict__ cm2, float* __restrict__ gstat)
{
    __shared__ __align__(16) char pool[18432];
    __shared__ float rs[4], rs2[4], mean_s, inv_s;
    const int blk = blockIdx.x;
    const int tid = threadIdx.x;

    if (blk < 128) {
        // ---- GN1 two-pass ----
        const int b = blk >> 5, g = blk & 31;
        const float* p = x + (size_t)blk * 16384;
        float s = 0.f, s2 = 0.f;
        for (int it = 0; it < 16; ++it) {
            int q = it * 256 + tid;
            float4 v = *(const float4*)&p[q * 4];
            s += v.x + v.y + v.z + v.w;
            s2 += v.x * v.x + v.y * v.y + v.z * v.z + v.w * v.w;
        }
        #pragma unroll
        for (int off = 32; off >= 1; off >>= 1) {
            s  += __shfl_down(s,  off, 64);
            s2 += __shfl_down(s2, off, 64);
        }
        const int wid = tid >> 6;
        if ((tid & 63) == 0) { rs[wid] = s; rs2[wid] = s2; }
        __syncthreads();
        if (tid == 0) {
            float S = rs[0] + rs[1] + rs[2] + rs[3];
            float S2 = rs2[0] + rs2[1] + rs2[2] + rs2[3];
            float m = S * (1.f / 16384.f);
            float var = S2 * (1.f / 16384.f) - m * m;
            mean_s = m;
            inv_s = rsqrtf(var + 1e-5f);
        }
        __syncthreads();
        const float m = mean_s, inv = inv_s;
        float sc[4], bi[4];
        #pragma unroll
        for (int j = 0; j < 4; ++j) { sc[j] = gn1s[g * 4 + j]; bi[j] = gn1b[g * 4 + j]; }
        for (int it = 0; it < 16; ++it) {
            int pp = it * 256 + tid;
            bf16x4 o;
            #pragma unroll
            for (int j = 0; j < 4; ++j)
                o[j] = (__bf16)silu_f((p[j * 4096 + pp] - m) * inv * sc[j] + bi[j]);
            *(bf16x4*)&aT[((size_t)(b * SP + pp)) * CC + g * 4] = o;
        }
    } else if (blk < 146) {
        // ---- weight transpose ----
        const int idx = blk - 128;
        const int wsel = idx / 9, tap = idx % 9;
        const float* src = wsel ? c2w : c1w;
        __bf16* dst = wt + (size_t)wsel * 9 * 16384 + (size_t)tap * 16384;
        for (int it = 0; it < 64; ++it) {
            int q = it * 256 + tid;
            dst[q] = (__bf16)src[(size_t)q * 9 + tap];
        }
    } else if (blk < 154) {
        // ---- temb MLP ----
        const int cog = blk - 146;
        float* st = (float*)pool;
        for (int it = 0; it < 8; ++it) {
            int q = it * 256 + tid;
            st[q] = silu_f(t[q]);
        }
        __syncthreads();
        const int col = tid >> 4, seg = tid & 15;
        const float* wr = mlpw + (size_t)(cog * 16 + col) * 512 + seg * 32;
        float acc[4] = {0.f, 0.f, 0.f, 0.f};
        #pragma unroll
        for (int k8 = 0; k8 < 8; ++k8) {
            float4 wv = *(const float4*)&wr[k8 * 4];
            #pragma unroll
            for (int j = 0; j < 4; ++j) {
                int k = seg * 32 + k8 * 4 + j;
                float w4 = (&wv.x)[j];
                acc[0] += st[0 * 512 + k] * w4;
                acc[1] += st[1 * 512 + k] * w4;
                acc[2] += st[2 * 512 + k] * w4;
                acc[3] += st[3 * 512 + k] * w4;
            }
        }
        #pragma unroll
        for (int o = 1; o < 16; o <<= 1) {
            #pragma unroll
            for (int b4 = 0; b4 < 4; ++b4)
                acc[b4] += __shfl_xor(acc[b4], o, 64);
        }
        if (seg == 0) {
            float bv = mlpb[cog * 16 + col];
            #pragma unroll
            for (int b4 = 0; b4 < 4; ++b4)
                tembw[b4 * 128 + cog * 16 + col] = acc[b4] + bv;
        }
    } else if (blk < 410) {
        // ---- 1x1 conv MFMA ----
        const int pblk = blk - 154;
        const int b = pblk >> 6;
        const int p0 = (pblk & 63) * 64;
        const int l = tid & 63, wv = tid >> 6;
        const int l15 = l & 15, l4 = l >> 4;
        const int mB = wv * 32;

        __bf16* XT = (__bf16*)pool;

        for (int it = 0; it < 32; ++it) {
            int q = it * 256 + tid;
            float v = cond[((size_t)(b * CC + (q >> 6))) * SP + p0 + (q & 63)];
            XT[(q & 63) * 136 + (q >> 6)] = (__bf16)v;
        }
        __syncthreads();

        f32x4 acc[2][4];
        #pragma unroll
        for (int mb = 0; mb < 2; ++mb)
            #pragma unroll
            for (int nt = 0; nt < 4; ++nt) acc[mb][nt] = (f32x4){0.f, 0.f, 0.f, 0.f};

        #pragma unroll
        for (int ks = 0; ks < 4; ++ks) {
            bf16x8 bfr[4];
            #pragma unroll
            for (int nt = 0; nt < 4; ++nt)
                bfr[nt] = *(const bf16x8*)&XT[(nt * 16 + l15) * 136 + ks * 32 + l4 * 8];
            #pragma unroll
            for (int mb = 0; mb < 2; ++mb) {
                const float* wrow = cw + (size_t)(mB + mb * 16 + l15) * 128 + ks * 32 + l4 * 8;
                float4 wa = *(const float4*)wrow;
                float4 wb4 = *(const float4*)(wrow + 4);
                bf16x8 afr;
                afr[0] = (__bf16)wa.x; afr[1] = (__bf16)wa.y;
                afr[2] = (__bf16)wa.z; afr[3] = (__bf16)wa.w;
                afr[4] = (__bf16)wb4.x; afr[5] = (__bf16)wb4.y;
                afr[6] = (__bf16)wb4.z; afr[7] = (__bf16)wb4.w;
                #pragma unroll
                for (int nt = 0; nt < 4; ++nt)
                    acc[mb][nt] = __builtin_amdgcn_mfma_f32_16x16x32_bf16(afr, bfr[nt], acc[mb][nt], 0, 0, 0);
            }
        }

        // scale = log2(e)/sqrt(128): folds the softmax temperature AND the
        // exp->exp2 conversion into the attention K operand (cmT is only ever
        // consumed as the QK^T A-operand in attn_kernel).
        const float scl = 0.12751743f;
        #pragma unroll
        for (int mb = 0; mb < 2; ++mb) {
            int co0 = mB + mb * 16 + l4 * 4;
            float bv[4];
            #pragma unroll
            for (int r = 0; r < 4; ++r) bv[r] = cb[co0 + r];
            #pragma unroll
            for (int nt = 0; nt < 4; ++nt) {
                int p = p0 + nt * 16 + l15;
                bf16x4 o;
                #pragma unroll
                for (int r = 0; r < 4; ++r)
                    o[r] = (__bf16)((acc[mb][nt][r] + bv[r]) * scl);
                *(bf16x4*)&cmT[((size_t)(b * SP + p)) * CC + co0] = o;
            }
        }
        __syncthreads();
        __bf16* O2 = (__bf16*)pool;
        #pragma unroll
        for (int mb = 0; mb < 2; ++mb) {
            int co0 = mB + mb * 16 + l4 * 4;
            #pragma unroll
            for (int r = 0; r < 4; ++r) {
                float bv = cb[co0 + r];
                #pragma unroll
                for (int nt = 0; nt < 4; ++nt)
                    O2[(co0 + r) * 72 + nt * 16 + l15] = (__bf16)(acc[mb][nt][r] + bv);
            }
        }
        __syncthreads();
        #pragma unroll
        for (int it = 0; it < 4; ++it) {
            int q = it * 256 + tid;
            int co = q >> 3, pc = q & 7;
            *(bf16x8*)&cm2[((size_t)(b * CC + co)) * SP + p0 + pc * 8] =
                *(const bf16x8*)&O2[co * 72 + pc * 8];
        }
    } else {
        // ---- gstat zero (replaces memset launch) ----
        gstat[tid] = 0.f;
    }
}

// ---------------- 3x3 conv v2: 512-thread blocks, all 128 co per block ----------------
template<bool FUSE_TEMB, bool OUT_CF, bool FUSE_GN>
__global__ __launch_bounds__(512, 4) void conv_mfma_kernel(
    const __bf16* __restrict__ inT, const __bf16* __restrict__ wt,
    const float* __restrict__ bias, const float* __restrict__ temb,
    const float* __restrict__ resid, __bf16* __restrict__ outT,
    float* __restrict__ outF, const float* __restrict__ gstat,
    const float* __restrict__ gn_s, const float* __restrict__ gn_b)
{
    const int y   = blockIdx.x >> 1;
    const int xh2 = blockIdx.x & 1;
    const int x0  = xh2 * 32;
    const int b   = blockIdx.y;
    const int tid = threadIdx.x;
    const int l = tid & 63, wv = tid >> 6;
    const int l15 = l & 15, l4 = l >> 4;
    const int co_w = wv * 16;            // 8 waves -> co 0..127

    __shared__ __bf16 inS[3 * 16 * 34 * 8];   // 26 KB
    __shared__ float af[128], bfp[128];

    if (FUSE_GN) {
        if (tid < 128) {
            int g = tid >> 2;
            float S = gstat[(b * NG + g) * 2], S2 = gstat[(b * NG + g) * 2 + 1];
            float m = S * (1.f / 16384.f);
            float var = S2 * (1.f / 16384.f) - m * m;
            float inv = rsqrtf(var + 1e-5f);
            float a = inv * gn_s[tid];
            af[tid] = a;
            bfp[tid] = gn_b[tid] - m * a;
        }
        __syncthreads();
    }

    const __bf16* inTb = inT + (size_t)b * SP * CC;
    for (int q = tid; q < 3 * 34 * 16; q += 512) {
        int cc = q & 15;
        int t2 = q >> 4;
        int xs = t2 % 34;
        int r  = t2 / 34;
        int yy = y + r - 1;
        int xg = x0 + xs - 1;
        bf16x8 v;
        if (((unsigned)yy < 64u) && ((unsigned)xg < 64u)) {
            bf16x8 raw = *(const bf16x8*)&inTb[((size_t)(yy * 64 + xg)) * CC + cc * 8];
            if (FUSE_GN) {
                #pragma unroll
                for (int j = 0; j < 8; ++j) {
                    int c = cc * 8 + j;
                    v[j] = (__bf16)silu_f((float)raw[j] * af[c] + bfp[c]);
                }
            } else {
                v = raw;
            }
        } else {
            #pragma unroll
            for (int j = 0; j < 8; ++j) v[j] = (__bf16)0.f;
        }
        *(bf16x8*)&inS[((r * 16 + cc) * 34 + xs) * 8] = v;
    }
    __syncthreads();

    f32x4 acc[2];
    acc[0] = (f32x4){0.f, 0.f, 0.f, 0.f};
    acc[1] = (f32x4){0.f, 0.f, 0.f, 0.f};

    const __bf16* wp = wt + (size_t)(co_w + l15) * 128 + l4 * 8;
    bf16x8 wb[2][4];
    #pragma unroll
    for (int ks = 0; ks < 4; ++ks)
        wb[0][ks] = *(const bf16x8*)(wp + ks * 32);

    #pragma unroll
    for (int tap = 0; tap < 9; ++tap) {
        const int cur = tap & 1, nxt = cur ^ 1;
        if (tap < 8) {
            #pragma unroll
            for (int ks = 0; ks < 4; ++ks)
                wb[nxt][ks] = *(const bf16x8*)(wp + (tap + 1) * 16384 + ks * 32);
        }
        const int rr = tap / 3, dx = tap % 3;
        #pragma unroll
        for (int ks = 0; ks < 4; ++ks) {
            const __bf16* rb = &inS[((rr * 16 + ks * 4 + l4) * 34) * 8];
            bf16x8 b0 = *(const bf16x8*)&rb[(dx + l15) * 8];
            bf16x8 b1 = *(const bf16x8*)&rb[(16 + dx + l15) * 8];
            acc[0] = __builtin_amdgcn_mfma_f32_16x16x32_bf16(wb[cur][ks], b0, acc[0], 0, 0, 0);
            acc[1] = __builtin_amdgcn_mfma_f32_16x16x32_bf16(wb[cur][ks], b1, acc[1], 0, 0, 0);
        }
    }

    if (OUT_CF) {
        #pragma unroll
        for (int r = 0; r < 4; ++r) {
            int co = co_w + l4 * 4 + r;
            float bv = bias[co];
            #pragma unroll
            for (int nb = 0; nb < 2; ++nb) {
                int p = y * 64 + x0 + nb * 16 + l15;
                size_t o = ((size_t)(b * CC + co)) * SP + p;
                outF[o] = acc[nb][r] + bv + resid[o];
            }
        }
    } else {
        int co0 = co_w + l4 * 4;
        float bv[4];
        #pragma unroll
        for (int r = 0; r < 4; ++r)
            bv[r] = bias[co0 + r] + (FUSE_TEMB ? temb[b * CC + co0 + r] : 0.f);
        #pragma unroll
        for (int nb = 0; nb < 2; ++nb) {
            int p = y * 64 + x0 + nb * 16 + l15;
            bf16x4 o;
            #pragma unroll
            for (int r = 0; r < 4; ++r)
                o[r] = (__bf16)(acc[nb][r] + bv[r]);
            *(bf16x4*)&outT[((size_t)(b * SP + p)) * CC + co0] = o;
        }
    }
}

// ---------------- fused cross-attention v18: dual-pipeline + fused GN2 stats ----------------
// 1024-thread blocks: waves 0-7 run the s=0 pipeline, waves 8-15 run s=1
// (each the proven v13 producer/consumer loop on its own 55.3KB LDS region).
// Grid 256 = 1 block/CU = 16 waves/CU (same wave count & 128-reg budget as
// v13's 2x512). The in-block epilogue computes h2 = h1 + att0 + att1 + emb,
// writes h2T (the old parts buffer; NOT cmT which other blocks still read),
// and does GN2 group sums -> deletes the gn2_stats kernel + 24MB of parts
// round-trip. XCD map b=bid&3: each XCD serves one b (K/V set 2MB < 4MB L2).
#define CT2 72    // ct2 row stride (bf16)
#define PBS 72    // Pb row stride (bf16)
#define PIPE_BYTES 55296   // per-pipeline: ct2[2] 2x18432 + Pb[2] 2x9216
#define NIT (SP / TT / NS)   // 32

__global__ __launch_bounds__(1024, 4) void attn_kernel(
    const __bf16* __restrict__ h1T, const __bf16* __restrict__ cmT,
    const __bf16* __restrict__ cm2, __bf16* __restrict__ h2T,
    const int* __restrict__ aim, const float* __restrict__ emb,
    float* __restrict__ gstat)
{
    const int bid = blockIdx.x;
    const int b = bid & 3;             // XCD-resident batch
    const int w = bid >> 2;            // 64 values
    const int tid = threadIdx.x;
    const int wid = tid >> 6;          // 0..15
    const int sg  = wid >> 3;          // pipeline = s
    const int wl  = wid & 7;           // wave within pipeline
    const int l = tid & 63, l15 = l & 15, l4 = l >> 4;
    const int s = sg;

    __shared__ __align__(16) char pool[2 * PIPE_BYTES];
    __shared__ float ls[16][16][4];
    char* base = pool + sg * PIPE_BYTES;
    __bf16* ct2p = (__bf16*)base;               // 2 buffers of 9216 elems
    __bf16* Pbp  = (__bf16*)(base + 36864);     // 2 buffers of 4608 elems

    const __bf16* h1Tb = h1T + (size_t)b * SP * CC;
    const __bf16* cmTb = cmT + (size_t)b * SP * CC;
    const __bf16* cm2b = cm2 + (size_t)b * CC * SP;

    if (wl < 4) {
        // ================= producer: QK^T + softmax =================
        const int pw = wl;    // owns 16 uv rows of each tile
        bf16x8 hfr[4][4];     // Q: 64h x 128c, register/AGPR-resident
        #pragma unroll
        for (int nt = 0; nt < 4; ++nt)
            #pragma unroll
            for (int ks = 0; ks < 4; ++ks)
                hfr[nt][ks] = *(const bf16x8*)&h1Tb[((size_t)((nt * 16 + l15) * WW + w)) * CC + ks * 32 + l4 * 8];

        bf16x8 afr[4];   // K fragments for the NEXT tile to produce

        // P(0) -> Pb[0], then issue K(1)
        {
            const int uv0 = s * TT;
            const __bf16* arow = cmTb + (size_t)(uv0 + 16 * pw + l15) * CC;
            bf16x8 a0[4];
            #pragma unroll
            for (int ks = 0; ks < 4; ++ks) a0[ks] = *(const bf16x8*)&arow[ks * 32 + l4 * 8];
            f32x4 s1[4];
            __builtin_amdgcn_s_setprio(1);
            #pragma unroll
            for (int nt = 0; nt < 4; ++nt) {
                s1[nt] = (f32x4){0.f, 0.f, 0.f, 0.f};
                #pragma unroll
                for (int ks = 0; ks < 4; ++ks)
                    s1[nt] = __builtin_amdgcn_mfma_f32_16x16x32_bf16(a0[ks], hfr[nt][ks], s1[nt], 0, 0, 0);
            }
            __builtin_amdgcn_s_setprio(0);
            // issue K(1) while softmax runs
            {
                const int uv1 = (NS + s) * TT;
                const __bf16* arow1 = cmTb + (size_t)(uv1 + 16 * pw + l15) * CC;
                #pragma unroll
                for (int ks = 0; ks < 4; ++ks) afr[ks] = *(const bf16x8*)&arow1[ks * 32 + l4 * 8];
            }
            #pragma unroll
            for (int r = 0; r < 4; ++r) {
                float e0 = fast_exp2(s1[0][r]), e1 = fast_exp2(s1[1][r]);
                float e2 = fast_exp2(s1[2][r]), e3 = fast_exp2(s1[3][r]);
                float sm = (e0 + e1) + (e2 + e3);
                sm = row16_sum(sm);
                float ri = 1.f / sm;
                s1[0][r] = e0 * ri; s1[1][r] = e1 * ri;
                s1[2][r] = e2 * ri; s1[3][r] = e3 * ri;
            }
            #pragma unroll
            for (int nt = 0; nt < 4; ++nt) {
                bf16x4 pk;
                pk[0] = (__bf16)s1[nt][0]; pk[1] = (__bf16)s1[nt][1];
                pk[2] = (__bf16)s1[nt][2]; pk[3] = (__bf16)s1[nt][3];
                *(bf16x4*)&Pbp[(nt * 16 + l15) * PBS + 16 * pw + l4 * 4] = pk;
            }
        }
        __syncthreads();   // #1: Pb[0] + ct2[0] ready (both pipelines)

        for (int i = 0; i < NIT; ++i) {
            if (i < NIT - 1) {
                // afr holds K(i+1) (issued >= 1 iteration ago)
                f32x4 s1[4];
                __builtin_amdgcn_s_setprio(1);
                #pragma unroll
                for (int nt = 0; nt < 4; ++nt) {
                    s1[nt] = (f32x4){0.f, 0.f, 0.f, 0.f};
                    #pragma unroll
                    for (int ks = 0; ks < 4; ++ks)
                        s1[nt] = __builtin_amdgcn_mfma_f32_16x16x32_bf16(afr[ks], hfr[nt][ks], s1[nt], 0, 0, 0);
                }
                __builtin_amdgcn_s_setprio(0);
                // re-issue K(i+2) immediately after last use of afr
                if (i < NIT - 2) {
                    const int uv2 = ((i + 2) * NS + s) * TT;
                    const __bf16* arow = cmTb + (size_t)(uv2 + 16 * pw + l15) * CC;
                    #pragma unroll
                    for (int ks = 0; ks < 4; ++ks) afr[ks] = *(const bf16x8*)&arow[ks * 32 + l4 * 8];
                }
                #pragma unroll
                for (int r = 0; r < 4; ++r) {
                    float e0 = fast_exp2(s1[0][r]), e1 = fast_exp2(s1[1][r]);
                    float e2 = fast_exp2(s1[2][r]), e3 = fast_exp2(s1[3][r]);
                    float sm = (e0 + e1) + (e2 + e3);
                    sm = row16_sum(sm);
                    float ri = 1.f / sm;
                    s1[0][r] = e0 * ri; s1[1][r] = e1 * ri;
                    s1[2][r] = e2 * ri; s1[3][r] = e3 * ri;
                }
                __bf16* PbW = Pbp + ((i & 1) ^ 1) * 4608;
                #pragma unroll
                for (int nt = 0; nt < 4; ++nt) {
                    bf16x4 pk;
                    pk[0] = (__bf16)s1[nt][0]; pk[1] = (__bf16)s1[nt][1];
                    pk[2] = (__bf16)s1[nt][2]; pk[3] = (__bf16)s1[nt][3];
                    *(bf16x4*)&PbW[(nt * 16 + l15) * PBS + 16 * pw + l4 * 4] = pk;
                }
            }
            __syncthreads();   // per-iter barrier (matches consumer)
        }
    } else {
        // ================= consumer: PV accumulate =================
        const int cw = wl - 4;
        const int hB = (cw & 1) * 32;
        const int cB = (cw >> 1) * 64;
        const int tc = tid & 255;       // 0..255 within consumer group
        const int sc = tc >> 3;
        const int stc = tc & 7;

        f32x4 acc2[2][4];
        #pragma unroll
        for (int mb = 0; mb < 2; ++mb)
            #pragma unroll
            for (int nt = 0; nt < 4; ++nt) acc2[mb][nt] = (f32x4){0.f, 0.f, 0.f, 0.f};

        bf16x8 st4[4];   // V fragments for the NEXT tile to stage

        // stage ct2[0] directly, then issue V(1)
        {
            const int uv0 = s * TT;
            #pragma unroll
            for (int it = 0; it < 4; ++it) {
                int c = it * 32 + sc;
                *(bf16x8*)&ct2p[c * CT2 + stc * 8] =
                    *(const bf16x8*)&cm2b[(size_t)c * SP + uv0 + stc * 8];
            }
            const int uv1 = (NS + s) * TT;
            #pragma unroll
            for (int it = 0; it < 4; ++it) {
                int c = it * 32 + sc;
                st4[it] = *(const bf16x8*)&cm2b[(size_t)c * SP + uv1 + stc * 8];
            }
        }
        __syncthreads();   // #1: Pb[0] + ct2[0] ready (both pipelines)

        for (int i = 0; i < NIT; ++i) {
            const int cur = i & 1;
            // consume tile i
            {
                const __bf16* PbR = Pbp + cur * 4608;
                const __bf16* ctR = ct2p + cur * 9216;
                bf16x8 pfr[2][2];
                #pragma unroll
                for (int mb = 0; mb < 2; ++mb)
                    #pragma unroll
                    for (int ks = 0; ks < 2; ++ks)
                        pfr[mb][ks] = *(const bf16x8*)&PbR[(hB + mb * 16 + l15) * PBS + ks * 32 + l4 * 8];
                bf16x8 bfr[4][2];
                #pragma unroll
                for (int nt = 0; nt < 4; ++nt)
                    #pragma unroll
                    for (int ks = 0; ks < 2; ++ks)
                        bfr[nt][ks] = *(const bf16x8*)&ctR[(cB + nt * 16 + l15) * CT2 + ks * 32 + l4 * 8];
                __builtin_amdgcn_s_setprio(1);
                #pragma unroll
                for (int mb = 0; mb < 2; ++mb)
                    #pragma unroll
                    for (int nt = 0; nt < 4; ++nt)
                        #pragma unroll
                        for (int ks = 0; ks < 2; ++ks)
                            acc2[mb][nt] = __builtin_amdgcn_mfma_f32_16x16x32_bf16(
                                pfr[mb][ks], bfr[nt][ks], acc2[mb][nt], 0, 0, 0);
                __builtin_amdgcn_s_setprio(0);
            }
            // write V(i+1) (in flight >= 1 iter) into the other LDS buffer,
            // then immediately issue V(i+2) into the drained st4 regs
            if (i < NIT - 1) {
                __bf16* ctW = ct2p + (cur ^ 1) * 9216;
                #pragma unroll
                for (int it = 0; it < 4; ++it) {
                    int c = it * 32 + sc;
                    *(bf16x8*)&ctW[c * CT2 + stc * 8] = st4[it];
                }
                if (i < NIT - 2) {
                    const int uv2 = ((i + 2) * NS + s) * TT;
                    #pragma unroll
                    for (int it = 0; it < 4; ++it) {
                        int c = it * 32 + sc;
                        st4[it] = *(const bf16x8*)&cm2b[(size_t)c * SP + uv2 + stc * 8];
                    }
                }
            }
            __syncthreads();   // per-iter barrier (matches producer)
        }

        // consumers stage output: Otr(sg) aliases this pipeline's pool region
        __bf16* Otr = (__bf16*)base;
        #pragma unroll
        for (int mb = 0; mb < 2; ++mb)
            #pragma unroll
            for (int nt = 0; nt < 4; ++nt)
                #pragma unroll
                for (int r = 0; r < 4; ++r)
                    Otr[(hB + mb * 16 + l4 * 4 + r) * 136 + cB + nt * 16 + l15] =
                        (__bf16)acc2[mb][nt][r];
    }

    __syncthreads();   // convergent: both Otr complete
    // ---------------- fused epilogue: h2 = h1 + att0 + att1 + emb ----------------
    {
        const __bf16* Otr0 = (const __bf16*)pool;
        const __bf16* Otr1 = (const __bf16*)(pool + PIPE_BYTES);
        const int h = tid >> 4, cc = tid & 15;
        const int off = h * 136 + cc * 8;
        bf16x8 o0 = *(const bf16x8*)&Otr0[off];
        bf16x8 o1 = *(const bf16x8*)&Otr1[off];
        size_t gbase = ((size_t)(b * SP + h * WW + w)) * CC + cc * 8;
        bf16x8 hv = *(const bf16x8*)&h1T[gbase];
        const float4 ev0 = *(const float4*)&emb[aim[b] * CC + cc * 8];
        const float4 ev1 = *(const float4*)&emb[aim[b] * CC + cc * 8 + 4];
        float v[8];
        #pragma unroll
        for (int j = 0; j < 4; ++j)
            v[j] = (float)hv[j] + (float)o0[j] + (float)o1[j] + (&ev0.x)[j];
        #pragma unroll
        for (int j = 4; j < 8; ++j)
            v[j] = (float)hv[j] + (float)o0[j] + (float)o1[j] + (&ev1.x)[j - 4];
        bf16x8 ov;
        #pragma unroll
        for (int j = 0; j < 8; ++j) ov[j] = (__bf16)v[j];
        *(bf16x8*)&h2T[gbase] = ov;
        // GN2 partial stats: this thread's 8 channels = groups cc*2, cc*2+1
        float sa = 0.f, s2a = 0.f, sb = 0.f, s2b = 0.f;
        #pragma unroll
        for (int j = 0; j < 4; ++j) { sa += v[j]; s2a += v[j] * v[j]; }
        #pragma unroll
        for (int j = 4; j < 8; ++j) { sb += v[j]; s2b += v[j] * v[j]; }
        // lanes l, l+16, l+32, l+48 share cc (different h) -> xor16/32
        sa  += __shfl_xor(sa,  16, 64); sa  += __shfl_xor(sa,  32, 64);
        s2a += __shfl_xor(s2a, 16, 64); s2a += __shfl_xor(s2a, 32, 64);
        sb  += __shfl_xor(sb,  16, 64); sb  += __shfl_xor(sb,  32, 64);
        s2b += __shfl_xor(s2b, 16, 64); s2b += __shfl_xor(s2b, 32, 64);
        if (l < 16) {
            ls[wid][l][0] = sa;  ls[wid][l][1] = s2a;
            ls[wid][l][2] = sb;  ls[wid][l][3] = s2b;
        }
    }
    __syncthreads();
    if (tid < 64) {
        const int cc = tid & 15, k = tid >> 4;   // k: 0=sumA 1=sqA 2=sumB 3=sqB
        float v = 0.f;
        #pragma unroll
        for (int wv = 0; wv < 16; ++wv) v += ls[wv][cc][k];
        const int g = cc * 2 + (k >> 1);
        atomicAdd(&gstat[(b * NG + g) * 2 + (k & 1)], v);
    }
}

extern "C" void kernel_launch(void* const* d_in, const int* in_sizes, int n_in,
                              void* d_out, int out_size, void* d_ws, size_t ws_size,
                              hipStream_t stream)
{
    const float* x     = (const float*)d_in[0];
    const float* t     = (const float*)d_in[1];
    const int*   aim   = (const int*)  d_in[2];
    const float* cond  = (const float*)d_in[3];
    const float* gn1s  = (const float*)d_in[4];
    const float* gn1b  = (const float*)d_in[5];
    const float* c1w   = (const float*)d_in[6];
    const float* c1b   = (const float*)d_in[7];
    const float* mlpw  = (const float*)d_in[8];
    const float* mlpb  = (const float*)d_in[9];
    const float* cw    = (const float*)d_in[10];
    const float* cb    = (const float*)d_in[11];
    const float* gn2s  = (const float*)d_in[12];
    const float* gn2b  = (const float*)d_in[13];
    const float* c2w   = (const float*)d_in[14];
    const float* c2b   = (const float*)d_in[15];
    const float* emb   = (const float*)d_in[16];
    float* out = (float*)d_out;
    float* ws = (float*)d_ws;

    // float-offset workspace map
    __bf16* aT    = (__bf16*)ws;                  // [0, 1048576)
    __bf16* h1T   = (__bf16*)(ws + 1048576);
    __bf16* cmT   = (__bf16*)(ws + 2097152);
    __bf16* cm2   = (__bf16*)(ws + 3145728);
    __bf16* h2T   = (__bf16*)(ws + 4194304);      // old parts buffer (cmT stays read-only during attn)
    __bf16* wt    = (__bf16*)(ws + 6291456);
    float*  tembw = ws + 6438912;
    float*  gstat = ws + 6439424;                 // 256 floats

    prep_kernel<<<dim3(411), dim3(256), 0, stream>>>(
        x, gn1s, gn1b, aT, c1w, c2w, wt, t, mlpw, mlpb, tembw,
        cond, cw, cb, cmT, cm2, gstat);
    conv_mfma_kernel<true, false, false><<<dim3(128, BB), dim3(512), 0, stream>>>(
        aT, wt, c1b, tembw, nullptr, h1T, nullptr, nullptr, nullptr, nullptr);
    attn_kernel<<<dim3(WW * BB), dim3(1024), 0, stream>>>(
        h1T, cmT, cm2, h2T, aim, emb, gstat);
    conv_mfma_kernel<false, true, true><<<dim3(128, BB), dim3(512), 0, stream>>>(
        h2T, wt + (size_t)9 * 16384, c2b, nullptr, x, nullptr, out, gstat, gn2s, gn2b);
}